// Round 6
// baseline (265.061 us; speedup 1.0000x reference)
//
#include <hip/hip_runtime.h>

#define S_DIM 4096
#define H_DIM 16
#define D_DIM 64
#define N_BLK 64          // S / 64 query blocks
#define NEG_INF_F (-1e30f)
#define QSCALE 0.125f     // 1/sqrt(64), exact

typedef __attribute__((ext_vector_type(4))) float f32x4;
typedef __attribute__((ext_vector_type(8))) short s16x8;
typedef __attribute__((ext_vector_type(4))) unsigned int u32x4;
typedef __attribute__((ext_vector_type(2))) unsigned int u32x2;

__device__ __forceinline__ unsigned int fbits(float f) {
    return __builtin_bit_cast(unsigned int, f);
}
// pack two floats -> two bf16 (round-half-up; inputs never NaN here). lo=a, hi=b
__device__ __forceinline__ unsigned int pkbf(float a, float b) {
    return __builtin_amdgcn_perm(fbits(b) + 0x8000u, fbits(a) + 0x8000u, 0x07060302u);
}

// SPLIT-K structure (R5) with a PRESSURE-MINIMIZED merge (R6 fix).
// 1 wave per query block = 2048 waves chip-wide = 2/SIMD -> latency-bound.
// Two waves per query block, split by KEY tiles (A: t=0..2, B: t=3..4),
// merged at the end: 4096 waves = 4/SIMD at VGPR<=128.
// Block = 8 waves (512 thr) = 4 query blocks x 2 split-K waves; V^T LDS 64KB
// shared; grid 512 = 2 blocks/CU = 16 waves/CU. __launch_bounds__(512,2):
// VGPR cap 128 (empirical hipcc cap = 256/min_waves_arg).
// R5 LESSON: the merge epilogue's live set (o[64]+sr+res+lmv+...) exceeded
// 128 -> compiler spilled the o accumulator (WRITE 33->164MB, dur 97us).
// R6 merge keeps peak live ~80 regs: compute s_own, scale o IN PLACE, write
// outgoing qts straight from o, accumulate partner INTO o, store. No held
// arrays across barriers.
// Main loop is EXACTLY R0's (fully-unrolled, continue-guarded; rolled/
// prefetch variants all regressed via spill or lost scheduling).
// V^T LDS layout: row d (0..63), 512 keys as 256 u32 bf16-pairs, column
// ROTATED by 8*d shorts (mod 512); 512-thread staging mapping has uniform d
// per 32-lane phase -> 0 bank conflicts (measured).
__global__ __launch_bounds__(512, 2) void bsattn_kernel(
    const float* __restrict__ qg, const float* __restrict__ kg,
    const float* __restrict__ vg, float* __restrict__ outg)
{
    __shared__ unsigned int lds_vt[D_DIM * 256];   // 64 KB: V^T bf16 pairs, rotated

    const int tid  = threadIdx.x;
    const int w    = tid >> 6;                   // 0..7
    const int lane = tid & 63;
    const int quad = lane >> 4;
    const int l16  = lane & 15;

    const int b    = blockIdx.z;
    const int h    = blockIdx.y;
    const int n0   = blockIdx.x << 2;
    const int p    = w >> 1;                     // query-block pair index 0..3
    const int wsub = w & 1;                      // 0: key tiles t=0..2, 1: t=3..4
    const int n    = n0 + p;                     // this wave's query block

    // ---- Q fragments (B-operand): bq[qt][hh], pre-scaled, bf16 ----
    s16x8 bq[4][2];
#pragma unroll
    for (int qt = 0; qt < 4; ++qt) {
        const size_t qrow = ((size_t)(b * S_DIM + n * 64 + qt * 16 + l16) * H_DIM + h) * D_DIM;
#pragma unroll
        for (int hh = 0; hh < 2; ++hh) {
            const float4* qp = reinterpret_cast<const float4*>(qg + qrow + hh * 32 + quad * 8);
            float4 f0 = qp[0];
            float4 f1 = qp[1];
            u32x4 u;
            u.x = pkbf(f0.x * QSCALE, f0.y * QSCALE);
            u.y = pkbf(f0.z * QSCALE, f0.w * QSCALE);
            u.z = pkbf(f1.x * QSCALE, f1.y * QSCALE);
            u.w = pkbf(f1.z * QSCALE, f1.w * QSCALE);
            bq[qt][hh] = __builtin_bit_cast(s16x8, u);
        }
    }

    // ---- V^T staging: wave w stages tile w; lane -> (row-pair sp, d-half dh) ----
    {
        const int jt = w;                        // 0..7 tile (wave-uniform)
        const int sp = lane & 31;                // row-pair index
        const int dh = lane >> 5;                // d-half (0: d<32, 1: d>=32)
        const int jv = n0 - 2 + jt;
        if (jv >= 0 && jv < N_BLK) {
            const float* v0p = vg + ((size_t)(b * S_DIM + jv * 64 + 2 * sp) * H_DIM + h) * D_DIM;
            const float* v1p = v0p + H_DIM * D_DIM;
            const int craw = jt * 64 + 2 * sp;   // raw column (key index) of this pair
#pragma unroll
            for (int ch = 0; ch < 2; ++ch) {     // 16 d-values per chunk
                const int d0 = dh * 32 + ch * 16;
                const float4* ap = reinterpret_cast<const float4*>(v0p + d0);
                const float4* bp = reinterpret_cast<const float4*>(v1p + d0);
                float4 a0 = ap[0], a1 = ap[1], a2 = ap[2], a3 = ap[3];
                float4 b0 = bp[0], b1 = bp[1], b2 = bp[2], b3 = bp[3];
                float av[16] = {a0.x,a0.y,a0.z,a0.w, a1.x,a1.y,a1.z,a1.w,
                                a2.x,a2.y,a2.z,a2.w, a3.x,a3.y,a3.z,a3.w};
                float bv[16] = {b0.x,b0.y,b0.z,b0.w, b1.x,b1.y,b1.z,b1.w,
                                b2.x,b2.y,b2.z,b2.w, b3.x,b3.y,b3.z,b3.w};
#pragma unroll
                for (int i = 0; i < 16; ++i) {
                    const int d = d0 + i;
                    lds_vt[d * 256 + (((craw + 8 * d) & 511) >> 1)] = pkbf(av[i], bv[i]);
                }
            }
        }
    }

    f32x4 o[4][4];                   // partial O accum [qt][dt] (row=query, col=d)
    float m_run[4], l_run[4];
#pragma unroll
    for (int qt = 0; qt < 4; ++qt) {
        m_run[qt] = NEG_INF_F; l_run[qt] = 0.f;
#pragma unroll
        for (int dt = 0; dt < 4; ++dt) o[qt][dt] = (f32x4){0.f, 0.f, 0.f, 0.f};
    }

    __syncthreads();                 // V^T visible; barrier-free main loop

    const int colb = quad * 4 + 8 * l16;     // read-column base (rotation part w/o tile/dt)

    for (int t = 0; t < 5; ++t) {
        if (wsub ? (t < 3) : (t >= 3)) continue;   // split-K: A owns t=0..2, B owns t=3..4
        const int j = n - 2 + t;             // key block (wave-uniform)
        if (j < 0 || j >= N_BLK) continue;
        const int ji = p + t;                // staged tile index = j - n0 + 2

        // ---- K A-fragments direct from global (coalesced 16-row x 128B chunks) ----
        float4 kf[4][2][2];
#pragma unroll
        for (int kt = 0; kt < 4; ++kt) {
            const size_t krow = ((size_t)(b * S_DIM + j * 64 + kt * 16 + l16) * H_DIM + h) * D_DIM + quad * 8;
#pragma unroll
            for (int hh = 0; hh < 2; ++hh) {
                const float4* kp = reinterpret_cast<const float4*>(kg + krow + hh * 32);
                kf[kt][hh][0] = kp[0];
                kf[kt][hh][1] = kp[1];
            }
        }
        s16x8 kbf[4][2];
#pragma unroll
        for (int kt = 0; kt < 4; ++kt)
#pragma unroll
            for (int hh = 0; hh < 2; ++hh) {
                u32x4 u;
                u.x = pkbf(kf[kt][hh][0].x, kf[kt][hh][0].y);
                u.y = pkbf(kf[kt][hh][0].z, kf[kt][hh][0].w);
                u.z = pkbf(kf[kt][hh][1].x, kf[kt][hh][1].y);
                u.w = pkbf(kf[kt][hh][1].z, kf[kt][hh][1].w);
                kbf[kt][hh] = __builtin_bit_cast(s16x8, u);
            }

        // ---- per qt: S^T = K x Q^T, online softmax; P stays in registers ----
        s16x8 pa[4][2];
#pragma unroll
        for (int qt = 0; qt < 4; ++qt) {
            f32x4 sa[4];
#pragma unroll
            for (int kt = 0; kt < 4; ++kt) {
                f32x4 z = {0.f, 0.f, 0.f, 0.f};
                f32x4 a0 = __builtin_amdgcn_mfma_f32_16x16x32_bf16(kbf[kt][0], bq[qt][0], z, 0, 0, 0);
                sa[kt]   = __builtin_amdgcn_mfma_f32_16x16x32_bf16(kbf[kt][1], bq[qt][1], a0, 0, 0, 0);
            }
            float mx = NEG_INF_F;
#pragma unroll
            for (int kt = 0; kt < 4; ++kt)
#pragma unroll
                for (int r = 0; r < 4; ++r) mx = fmaxf(mx, sa[kt][r]);
            mx = fmaxf(mx, __shfl_xor(mx, 16));
            mx = fmaxf(mx, __shfl_xor(mx, 32));
            const float mn = fmaxf(m_run[qt], mx);
            const float alpha = __expf(m_run[qt] - mn);
            m_run[qt] = mn;

            float rs = 0.f;
            unsigned int pk[4][2];
#pragma unroll
            for (int kt = 0; kt < 4; ++kt) {
                float e0 = __expf(sa[kt][0] - mn);
                float e1 = __expf(sa[kt][1] - mn);
                float e2 = __expf(sa[kt][2] - mn);
                float e3 = __expf(sa[kt][3] - mn);
                rs += (e0 + e1) + (e2 + e3);
                pk[kt][0] = pkbf(e0, e1);
                pk[kt][1] = pkbf(e2, e3);
            }
            rs += __shfl_xor(rs, 16);
            rs += __shfl_xor(rs, 32);
            l_run[qt] = l_run[qt] * alpha + rs;

            float ab[4];
#pragma unroll
            for (int r = 0; r < 4; ++r)
                ab[r] = __shfl(alpha, (lane & 48) + quad * 4 + r);
#pragma unroll
            for (int dt = 0; dt < 4; ++dt)
#pragma unroll
                for (int r = 0; r < 4; ++r) o[qt][dt][r] *= ab[r];

            pa[qt][0] = __builtin_bit_cast(s16x8, (u32x4){pk[0][0], pk[0][1], pk[1][0], pk[1][1]});
            pa[qt][1] = __builtin_bit_cast(s16x8, (u32x4){pk[2][0], pk[2][1], pk[3][0], pk[3][1]});
        }

        // ---- PV: O += P x V (B-frags from rotated V^T LDS, permuted key order) ----
        const int cb0 = ji * 64 + colb;
#pragma unroll
        for (int dt = 0; dt < 4; ++dt) {
            const int d = dt * 16 + l16;
            const unsigned int* vrow = lds_vt + d * 256;
            const int cb = cb0 + 128 * dt;
            u32x2 v00 = *reinterpret_cast<const u32x2*>(vrow + (((cb     ) & 511) >> 1));
            u32x2 v01 = *reinterpret_cast<const u32x2*>(vrow + (((cb + 16) & 511) >> 1));
            u32x2 v10 = *reinterpret_cast<const u32x2*>(vrow + (((cb + 32) & 511) >> 1));
            u32x2 v11 = *reinterpret_cast<const u32x2*>(vrow + (((cb + 48) & 511) >> 1));
            s16x8 vf0 = __builtin_bit_cast(s16x8, (u32x4){v00.x, v00.y, v01.x, v01.y});
            s16x8 vf1 = __builtin_bit_cast(s16x8, (u32x4){v10.x, v10.y, v11.x, v11.y});
#pragma unroll
            for (int qt = 0; qt < 4; ++qt) {
                o[qt][dt] = __builtin_amdgcn_mfma_f32_16x16x32_bf16(pa[qt][0], vf0, o[qt][dt], 0, 0, 0);
                o[qt][dt] = __builtin_amdgcn_mfma_f32_16x16x32_bf16(pa[qt][1], vf1, o[qt][dt], 0, 0, 0);
            }
        }
    }

    // ======== split-K merge, pressure-minimized (reuses dead lds_vt) ========
    __syncthreads();                                   // all PV reads of V^T done
    float* lbuf = reinterpret_cast<float*>(lds_vt);

    // phase 1: exchange m,l. [pair][half][qt][l16][2] floats (4 KB).
    if (quad == 0) {
#pragma unroll
        for (int qt = 0; qt < 4; ++qt) {
            const int base = ((((p << 1) + wsub) * 4 + qt) * 16 + l16) * 2;
            lbuf[base]     = m_run[qt];
            lbuf[base + 1] = l_run[qt];
        }
    }
    __syncthreads();

    // read partner m,l; s_own = exp(m_own - max); SCALE o IN PLACE immediately.
    // invl only for my 2 finalized qts. Empty partner (n=63 wave B): mP=-1e30,
    // lP=0 -> its s=0 / our s=1 -> correct.
    float invl[2];
#pragma unroll
    for (int qt = 0; qt < 4; ++qt) {
        const int pb = ((((p << 1) + (wsub ^ 1)) * 4 + qt) * 16 + l16) * 2;
        const float mP = lbuf[pb], lP = lbuf[pb + 1];
        const float mm = fmaxf(m_run[qt], mP);
        const float so = __expf(m_run[qt] - mm);
        if ((qt >> 1) == wsub)
            invl[qt & 1] = 1.0f / (l_run[qt] * so + lP * __expf(mP - mm));
        // broadcast so from softmax layout (owner lane l16=query) to row layout
#pragma unroll
        for (int r = 0; r < 4; ++r) {
            const float sr = __shfl(so, (lane & 48) + quad * 4 + r);
#pragma unroll
            for (int dt = 0; dt < 4; ++dt) o[qt][dt][r] *= sr;
        }
    }
    __syncthreads();                                   // ml reads done before overwrite

    // phase 2: write my OUTGOING scaled partials (the 2 qts my partner finalizes)
    // straight from o. Layout [pair][qt][dt][lane] f32x4 (64 KB exact).
    const int qo0 = (wsub ^ 1) << 1;
#pragma unroll
    for (int qq = 0; qq < 2; ++qq) {
        const int qt = qo0 + qq;
#pragma unroll
        for (int dt = 0; dt < 4; ++dt)
            *reinterpret_cast<f32x4*>(lbuf + ((((p << 2) + qt) * 4 + dt) * 64 + lane) * 4) = o[qt][dt];
    }
    __syncthreads();

    // phase 3: my 2 qts: accumulate partner INTO o, normalize, store.
    const int qm0 = wsub << 1;
#pragma unroll
    for (int qq = 0; qq < 2; ++qq) {
        const int qt = qm0 + qq;
#pragma unroll
        for (int dt = 0; dt < 4; ++dt) {
            const f32x4 oth = *reinterpret_cast<const f32x4*>(
                lbuf + ((((p << 2) + qt) * 4 + dt) * 64 + lane) * 4);
#pragma unroll
            for (int r = 0; r < 4; ++r) o[qt][dt][r] += oth[r];
        }
#pragma unroll
        for (int r = 0; r < 4; ++r) {
            const float ir = __shfl(invl[qq], (lane & 48) + quad * 4 + r);
            const int row = n * 64 + qt * 16 + quad * 4 + r;
            float* op = outg + ((size_t)(b * S_DIM + row) * H_DIM + h) * D_DIM + l16;
#pragma unroll
            for (int dt = 0; dt < 4; ++dt)
                op[dt * 16] = o[qt][dt][r] * ir;
        }
    }
}

extern "C" void kernel_launch(void* const* d_in, const int* in_sizes, int n_in,
                              void* d_out, int out_size, void* d_ws, size_t ws_size,
                              hipStream_t stream) {
    const float* q = (const float*)d_in[0];
    const float* k = (const float*)d_in[1];
    const float* v = (const float*)d_in[2];
    float* out = (float*)d_out;
    const int B = in_sizes[0] / (S_DIM * H_DIM * D_DIM);   // = 2
    dim3 grid(N_BLK / 4, H_DIM, B);
    dim3 block(512);
    hipLaunchKernelGGL(bsattn_kernel, grid, block, 0, stream, q, k, v, out);
}

// Round 7
// 173.253 us; speedup vs baseline: 1.5299x; 1.5299x over previous
//
#include <hip/hip_runtime.h>

#define S_DIM 4096
#define H_DIM 16
#define D_DIM 64
#define N_BLK 64          // S / 64 query blocks
#define NEG_INF_F (-1e30f)
#define QSCALE 0.125f     // 1/sqrt(64), exact

typedef __attribute__((ext_vector_type(4))) float f32x4;
typedef __attribute__((ext_vector_type(8))) short s16x8;
typedef __attribute__((ext_vector_type(4))) unsigned int u32x4;
typedef __attribute__((ext_vector_type(2))) unsigned int u32x2;

__device__ __forceinline__ unsigned int fbits(float f) {
    return __builtin_bit_cast(unsigned int, f);
}
// pack two floats -> two bf16 (round-half-up; inputs never NaN here). lo=a, hi=b
__device__ __forceinline__ unsigned int pkbf(float a, float b) {
    return __builtin_amdgcn_perm(fbits(b) + 0x8000u, fbits(a) + 0x8000u, 0x07060302u);
}

// Issue the 8 coalesced dwordx4 loads for one K tile (16-row x 128B chunks).
__device__ __forceinline__ void load_k(const float* __restrict__ kb, float4 (&kf)[4][2][2]) {
#pragma unroll
    for (int kt = 0; kt < 4; ++kt) {
        const float4* kp = reinterpret_cast<const float4*>(kb + (size_t)kt * (16 * H_DIM * D_DIM));
#pragma unroll
        for (int hh = 0; hh < 2; ++hh) {
            kf[kt][hh][0] = kp[hh * 8 + 0];
            kf[kt][hh][1] = kp[hh * 8 + 1];
        }
    }
}

__device__ __forceinline__ void conv_k(const float4 (&kf)[4][2][2], s16x8 (&kbf)[4][2]) {
#pragma unroll
    for (int kt = 0; kt < 4; ++kt)
#pragma unroll
        for (int hh = 0; hh < 2; ++hh) {
            u32x4 u;
            u.x = pkbf(kf[kt][hh][0].x, kf[kt][hh][0].y);
            u.y = pkbf(kf[kt][hh][0].z, kf[kt][hh][0].w);
            u.z = pkbf(kf[kt][hh][1].x, kf[kt][hh][1].y);
            u.w = pkbf(kf[kt][hh][1].z, kf[kt][hh][1].w);
            kbf[kt][hh] = __builtin_bit_cast(s16x8, u);
        }
}

// One key-tile body: S^T = K x Q^T, online softmax (max as depth-4 tree --
// exactly associative, replaces the 16-deep sequential fmax chain), PV from
// rotated V^T LDS. Identical math to R0.
__device__ __forceinline__ void compute_tile(
    const s16x8 (&kbf)[4][2], const s16x8 (&bq)[4][2],
    f32x4 (&o)[4][4], float (&m_run)[4], float (&l_run)[4],
    const unsigned int* __restrict__ lds_vt, int cb0, int lane, int quad)
{
    s16x8 pa[4][2];
#pragma unroll
    for (int qt = 0; qt < 4; ++qt) {
        f32x4 sa[4];
#pragma unroll
        for (int kt = 0; kt < 4; ++kt) {
            f32x4 z = {0.f, 0.f, 0.f, 0.f};
            f32x4 a0 = __builtin_amdgcn_mfma_f32_16x16x32_bf16(kbf[kt][0], bq[qt][0], z, 0, 0, 0);
            sa[kt]   = __builtin_amdgcn_mfma_f32_16x16x32_bf16(kbf[kt][1], bq[qt][1], a0, 0, 0, 0);
        }
        // depth-4 max tree (4 independent per-kt maxes, then combine)
        const float ma = fmaxf(fmaxf(sa[0][0], sa[0][1]), fmaxf(sa[0][2], sa[0][3]));
        const float mb = fmaxf(fmaxf(sa[1][0], sa[1][1]), fmaxf(sa[1][2], sa[1][3]));
        const float mc = fmaxf(fmaxf(sa[2][0], sa[2][1]), fmaxf(sa[2][2], sa[2][3]));
        const float md = fmaxf(fmaxf(sa[3][0], sa[3][1]), fmaxf(sa[3][2], sa[3][3]));
        float mx = fmaxf(fmaxf(ma, mb), fmaxf(mc, md));
        mx = fmaxf(mx, __shfl_xor(mx, 16));
        mx = fmaxf(mx, __shfl_xor(mx, 32));
        const float mn = fmaxf(m_run[qt], mx);
        const float alpha = __expf(m_run[qt] - mn);
        m_run[qt] = mn;

        float rsk[4];
        unsigned int pk[4][2];
#pragma unroll
        for (int kt = 0; kt < 4; ++kt) {
            float e0 = __expf(sa[kt][0] - mn);
            float e1 = __expf(sa[kt][1] - mn);
            float e2 = __expf(sa[kt][2] - mn);
            float e3 = __expf(sa[kt][3] - mn);
            rsk[kt] = (e0 + e1) + (e2 + e3);
            pk[kt][0] = pkbf(e0, e1);
            pk[kt][1] = pkbf(e2, e3);
        }
        float rs = (rsk[0] + rsk[1]) + (rsk[2] + rsk[3]);
        rs += __shfl_xor(rs, 16);
        rs += __shfl_xor(rs, 32);
        l_run[qt] = l_run[qt] * alpha + rs;

        float ab[4];
#pragma unroll
        for (int r = 0; r < 4; ++r)
            ab[r] = __shfl(alpha, (lane & 48) + quad * 4 + r);
#pragma unroll
        for (int dt = 0; dt < 4; ++dt)
#pragma unroll
            for (int r = 0; r < 4; ++r) o[qt][dt][r] *= ab[r];

        pa[qt][0] = __builtin_bit_cast(s16x8, (u32x4){pk[0][0], pk[0][1], pk[1][0], pk[1][1]});
        pa[qt][1] = __builtin_bit_cast(s16x8, (u32x4){pk[2][0], pk[2][1], pk[3][0], pk[3][1]});
    }

    // PV: O += P x V (B-frags from rotated V^T LDS, permuted key order)
    const int l16 = lane & 15;
#pragma unroll
    for (int dt = 0; dt < 4; ++dt) {
        const int d = dt * 16 + l16;
        const unsigned int* vrow = lds_vt + d * 256;
        const int cb = cb0 + 128 * dt;
        u32x2 v00 = *reinterpret_cast<const u32x2*>(vrow + (((cb     ) & 511) >> 1));
        u32x2 v01 = *reinterpret_cast<const u32x2*>(vrow + (((cb + 16) & 511) >> 1));
        u32x2 v10 = *reinterpret_cast<const u32x2*>(vrow + (((cb + 32) & 511) >> 1));
        u32x2 v11 = *reinterpret_cast<const u32x2*>(vrow + (((cb + 48) & 511) >> 1));
        s16x8 vf0 = __builtin_bit_cast(s16x8, (u32x4){v00.x, v00.y, v01.x, v01.y});
        s16x8 vf1 = __builtin_bit_cast(s16x8, (u32x4){v10.x, v10.y, v11.x, v11.y});
#pragma unroll
        for (int qt = 0; qt < 4; ++qt) {
            o[qt][dt] = __builtin_amdgcn_mfma_f32_16x16x32_bf16(pa[qt][0], vf0, o[qt][dt], 0, 0, 0);
            o[qt][dt] = __builtin_amdgcn_mfma_f32_16x16x32_bf16(pa[qt][1], vf1, o[qt][dt], 0, 0, 0);
        }
    }
}

// R0 structure (best measured: 65.8us) + straight-line double-buffered K
// prefetch. Block = 4 waves; wave w owns the FULL query block n = n0 + w
// (4 independent qt softmax chains of ILP -- R2's qt-split halved this and
// regressed; R5/R6's split-K merge spilled the o accumulator at the 128 cap).
// THE STALL (R0 counters): per tile, 8 K-loads are issued then immediately
// consumed -> vmcnt(0) wait of L2/HBM latency x5 tiles with only 2 waves/SIMD
// to cover it; memory duty cycle ~15%, all pipes <26%.
// FIX: two named K buffers (kfA/kfB, no dynamic indexing), fully unrolled
// 5-tile straight-line body. Top of tile t issues tile t+1's loads (clamped j,
// in flight through QK+softmax+PV ~2.5K cy); bottom converts them.
// __launch_bounds__(256,1): VGPR cap 256 (empirical hipcc cap =
// 256/min_waves_arg; R0's (256,2)=128 cap is exactly what stopped the
// compiler from pipelining on its own -- VGPR_Count was pinned at 120-128).
// LDS (64KB -> 2 blocks/CU = 2 waves/SIMD) caps occupancy for ANY VGPR<=256,
// so the extra ~80 regs are free. Tripwire: WRITE_SIZE>40MB = spill.
// V^T LDS layout: row d (0..63), 512 keys as 256 u32 bf16-pairs, column
// ROTATED by 8*d shorts (mod 512); staging mapping gives 0 bank conflicts
// (measured R0).
__global__ __launch_bounds__(256, 1) void bsattn_kernel(
    const float* __restrict__ qg, const float* __restrict__ kg,
    const float* __restrict__ vg, float* __restrict__ outg)
{
    __shared__ unsigned int lds_vt[D_DIM * 256];   // 64 KB: V^T bf16 pairs, rotated

    const int tid  = threadIdx.x;
    const int w    = tid >> 6;
    const int lane = tid & 63;
    const int quad = lane >> 4;
    const int l16  = lane & 15;

    const int b  = blockIdx.z;
    const int h  = blockIdx.y;
    const int n0 = blockIdx.x << 2;
    const int n  = n0 + w;                       // this wave's query block

    const float* kbase = kg + ((size_t)(b * S_DIM) * H_DIM + h) * D_DIM + ((size_t)l16 * H_DIM) * D_DIM + quad * 8;
    // per-tile K pointer: kbase + j*64*H*D
#define KPTR(jj) (kbase + (size_t)(jj) * (64 * H_DIM * D_DIM))
#define JCLAMP(jj) ((jj) < 0 ? 0 : ((jj) > (N_BLK - 1) ? (N_BLK - 1) : (jj)))

    // ---- pipeline prologue: issue K loads for tile 0 (clamped) first ----
    float4 kfA[4][2][2], kfB[4][2][2];
    s16x8 kbf[4][2];
    load_k(KPTR(JCLAMP(n - 2)), kfA);

    // ---- Q fragments (B-operand): bq[qt][hh], pre-scaled, bf16 ----
    s16x8 bq[4][2];
#pragma unroll
    for (int qt = 0; qt < 4; ++qt) {
        const size_t qrow = ((size_t)(b * S_DIM + n * 64 + qt * 16 + l16) * H_DIM + h) * D_DIM;
#pragma unroll
        for (int hh = 0; hh < 2; ++hh) {
            const float4* qp = reinterpret_cast<const float4*>(qg + qrow + hh * 32 + quad * 8);
            float4 f0 = qp[0];
            float4 f1 = qp[1];
            u32x4 u;
            u.x = pkbf(f0.x * QSCALE, f0.y * QSCALE);
            u.y = pkbf(f0.z * QSCALE, f0.w * QSCALE);
            u.z = pkbf(f1.x * QSCALE, f1.y * QSCALE);
            u.w = pkbf(f1.z * QSCALE, f1.w * QSCALE);
            bq[qt][hh] = __builtin_bit_cast(s16x8, u);
        }
    }

    // ---- V^T staging: 8 tiles, once. thread -> (tile jt, row pair 2sp,2sp+1) ----
    {
        const int jt = tid >> 5;                 // 0..7
        const int sp = tid & 31;                 // row-pair index
        const int jv = n0 - 2 + jt;
        if (jv >= 0 && jv < N_BLK) {
            const float* v0p = vg + ((size_t)(b * S_DIM + jv * 64 + 2 * sp) * H_DIM + h) * D_DIM;
            const float* v1p = v0p + H_DIM * D_DIM;
            const int craw = jt * 64 + 2 * sp;   // raw column (key index) of this pair
#pragma unroll
            for (int ch = 0; ch < 4; ++ch) {     // 16 d-values per chunk (bounds transient regs)
                const int d0 = ch * 16;
                const float4* ap = reinterpret_cast<const float4*>(v0p + d0);
                const float4* bp = reinterpret_cast<const float4*>(v1p + d0);
                float4 a0 = ap[0], a1 = ap[1], a2 = ap[2], a3 = ap[3];
                float4 b0 = bp[0], b1 = bp[1], b2 = bp[2], b3 = bp[3];
                float av[16] = {a0.x,a0.y,a0.z,a0.w, a1.x,a1.y,a1.z,a1.w,
                                a2.x,a2.y,a2.z,a2.w, a3.x,a3.y,a3.z,a3.w};
                float bv[16] = {b0.x,b0.y,b0.z,b0.w, b1.x,b1.y,b1.z,b1.w,
                                b2.x,b2.y,b2.z,b2.w, b3.x,b3.y,b3.z,b3.w};
#pragma unroll
                for (int i = 0; i < 16; ++i) {
                    const int d = d0 + i;
                    lds_vt[d * 256 + (((craw + 8 * d) & 511) >> 1)] = pkbf(av[i], bv[i]);
                }
            }
        }
    }

    f32x4 o[4][4];                   // O accum [qt][dt], C layout (row=query, col=d)
    float m_run[4], l_run[4];
#pragma unroll
    for (int qt = 0; qt < 4; ++qt) {
        m_run[qt] = NEG_INF_F; l_run[qt] = 0.f;
#pragma unroll
        for (int dt = 0; dt < 4; ++dt) o[qt][dt] = (f32x4){0.f, 0.f, 0.f, 0.f};
    }

    __syncthreads();                 // V^T visible; no further barriers

    const int colb = quad * 4 + 8 * l16;     // read-column base (rotation part w/o tile/dt)

    conv_k(kfA, kbf);                // tile 0 bf16 ready (loads long since landed)

    // ---- tile 0 (j = n-2): prefetch t=1 into kfB, compute, convert kfB ----
    load_k(KPTR(JCLAMP(n - 1)), kfB);
    if (n - 2 >= 0)
        compute_tile(kbf, bq, o, m_run, l_run, lds_vt, (w + 0) * 64 + colb, lane, quad);
    conv_k(kfB, kbf);

    // ---- tile 1 (j = n-1): prefetch t=2 into kfA ----
    load_k(KPTR(JCLAMP(n)), kfA);
    if (n - 1 >= 0)
        compute_tile(kbf, bq, o, m_run, l_run, lds_vt, (w + 1) * 64 + colb, lane, quad);
    conv_k(kfA, kbf);

    // ---- tile 2 (j = n, always valid): prefetch t=3 into kfB ----
    load_k(KPTR(JCLAMP(n + 1)), kfB);
    compute_tile(kbf, bq, o, m_run, l_run, lds_vt, (w + 2) * 64 + colb, lane, quad);
    conv_k(kfB, kbf);

    // ---- tile 3 (j = n+1): prefetch t=4 into kfA ----
    load_k(KPTR(JCLAMP(n + 2)), kfA);
    if (n + 1 < N_BLK)
        compute_tile(kbf, bq, o, m_run, l_run, lds_vt, (w + 3) * 64 + colb, lane, quad);
    conv_k(kfA, kbf);

    // ---- tile 4 (j = n+2): no prefetch ----
    if (n + 2 < N_BLK)
        compute_tile(kbf, bq, o, m_run, l_run, lds_vt, (w + 4) * 64 + colb, lane, quad);

#undef KPTR
#undef JCLAMP

    // ---- epilogue: broadcast l to row layout, normalize, store ----
#pragma unroll
    for (int qt = 0; qt < 4; ++qt) {
#pragma unroll
        for (int r = 0; r < 4; ++r) {
            const float lb = __shfl(l_run[qt], (lane & 48) + quad * 4 + r);
            const float inv = 1.0f / lb;
            const int row = n * 64 + qt * 16 + quad * 4 + r;
            float* op = outg + ((size_t)(b * S_DIM + row) * H_DIM + h) * D_DIM + l16;
#pragma unroll
            for (int dt = 0; dt < 4; ++dt)
                op[dt * 16] = o[qt][dt][r] * inv;
        }
    }
}

extern "C" void kernel_launch(void* const* d_in, const int* in_sizes, int n_in,
                              void* d_out, int out_size, void* d_ws, size_t ws_size,
                              hipStream_t stream) {
    const float* q = (const float*)d_in[0];
    const float* k = (const float*)d_in[1];
    const float* v = (const float*)d_in[2];
    float* out = (float*)d_out;
    const int B = in_sizes[0] / (S_DIM * H_DIM * D_DIM);   // = 2
    dim3 grid(N_BLK / 4, H_DIM, B);
    dim3 block(256);
    hipLaunchKernelGGL(bsattn_kernel, grid, block, 0, stream, q, k, v, out);
}

// Round 8
// 167.443 us; speedup vs baseline: 1.5830x; 1.0347x over previous
//
#include <hip/hip_runtime.h>

#define S_DIM 4096
#define H_DIM 16
#define D_DIM 64
#define N_BLK 64          // S / 64 query blocks
#define NEG_INF_F (-1e30f)
#define QSCALE 0.125f     // 1/sqrt(64), exact

typedef __attribute__((ext_vector_type(4))) float f32x4;
typedef __attribute__((ext_vector_type(8))) short s16x8;
typedef __attribute__((ext_vector_type(4))) unsigned int u32x4;
typedef __attribute__((ext_vector_type(2))) unsigned int u32x2;

__device__ __forceinline__ unsigned int fbits(float f) {
    return __builtin_bit_cast(unsigned int, f);
}
// pack two floats -> two bf16 (round-half-up; inputs never NaN here). lo=a, hi=b
__device__ __forceinline__ unsigned int pkbf(float a, float b) {
    return __builtin_amdgcn_perm(fbits(b) + 0x8000u, fbits(a) + 0x8000u, 0x07060302u);
}

// One key-tile body: S^T = K x Q^T, online softmax (depth-4 max tree, exactly
// associative), PV from rotated V^T LDS. Math identical to R0 (absmax-matched).
__device__ __forceinline__ void compute_tile(
    const s16x8 (&kbf)[4][2], const s16x8 (&bq)[4][2],
    f32x4 (&o)[4][4], float (&m_run)[4], float (&l_run)[4],
    const unsigned int* __restrict__ lds_vt, int cb0, int lane, int quad)
{
    s16x8 pa[4][2];
#pragma unroll
    for (int qt = 0; qt < 4; ++qt) {
        f32x4 sa[4];
#pragma unroll
        for (int kt = 0; kt < 4; ++kt) {
            f32x4 z = {0.f, 0.f, 0.f, 0.f};
            f32x4 a0 = __builtin_amdgcn_mfma_f32_16x16x32_bf16(kbf[kt][0], bq[qt][0], z, 0, 0, 0);
            sa[kt]   = __builtin_amdgcn_mfma_f32_16x16x32_bf16(kbf[kt][1], bq[qt][1], a0, 0, 0, 0);
        }
        const float ma = fmaxf(fmaxf(sa[0][0], sa[0][1]), fmaxf(sa[0][2], sa[0][3]));
        const float mb = fmaxf(fmaxf(sa[1][0], sa[1][1]), fmaxf(sa[1][2], sa[1][3]));
        const float mc = fmaxf(fmaxf(sa[2][0], sa[2][1]), fmaxf(sa[2][2], sa[2][3]));
        const float md = fmaxf(fmaxf(sa[3][0], sa[3][1]), fmaxf(sa[3][2], sa[3][3]));
        float mx = fmaxf(fmaxf(ma, mb), fmaxf(mc, md));
        mx = fmaxf(mx, __shfl_xor(mx, 16));
        mx = fmaxf(mx, __shfl_xor(mx, 32));
        const float mn = fmaxf(m_run[qt], mx);
        const float alpha = __expf(m_run[qt] - mn);
        m_run[qt] = mn;

        float rsk[4];
        unsigned int pk[4][2];
#pragma unroll
        for (int kt = 0; kt < 4; ++kt) {
            float e0 = __expf(sa[kt][0] - mn);
            float e1 = __expf(sa[kt][1] - mn);
            float e2 = __expf(sa[kt][2] - mn);
            float e3 = __expf(sa[kt][3] - mn);
            rsk[kt] = (e0 + e1) + (e2 + e3);
            pk[kt][0] = pkbf(e0, e1);
            pk[kt][1] = pkbf(e2, e3);
        }
        float rs = (rsk[0] + rsk[1]) + (rsk[2] + rsk[3]);
        rs += __shfl_xor(rs, 16);
        rs += __shfl_xor(rs, 32);
        l_run[qt] = l_run[qt] * alpha + rs;

        float ab[4];
#pragma unroll
        for (int r = 0; r < 4; ++r)
            ab[r] = __shfl(alpha, (lane & 48) + quad * 4 + r);
#pragma unroll
        for (int dt = 0; dt < 4; ++dt)
#pragma unroll
            for (int r = 0; r < 4; ++r) o[qt][dt][r] *= ab[r];

        pa[qt][0] = __builtin_bit_cast(s16x8, (u32x4){pk[0][0], pk[0][1], pk[1][0], pk[1][1]});
        pa[qt][1] = __builtin_bit_cast(s16x8, (u32x4){pk[2][0], pk[2][1], pk[3][0], pk[3][1]});
    }

    // PV: O += P x V (B-frags from rotated V^T LDS, permuted key order)
    const int l16 = lane & 15;
#pragma unroll
    for (int dt = 0; dt < 4; ++dt) {
        const int d = dt * 16 + l16;
        const unsigned int* vrow = lds_vt + d * 256;
        const int cb = cb0 + 128 * dt;
        u32x2 v00 = *reinterpret_cast<const u32x2*>(vrow + (((cb     ) & 511) >> 1));
        u32x2 v01 = *reinterpret_cast<const u32x2*>(vrow + (((cb + 16) & 511) >> 1));
        u32x2 v10 = *reinterpret_cast<const u32x2*>(vrow + (((cb + 32) & 511) >> 1));
        u32x2 v11 = *reinterpret_cast<const u32x2*>(vrow + (((cb + 48) & 511) >> 1));
        s16x8 vf0 = __builtin_bit_cast(s16x8, (u32x4){v00.x, v00.y, v01.x, v01.y});
        s16x8 vf1 = __builtin_bit_cast(s16x8, (u32x4){v10.x, v10.y, v11.x, v11.y});
#pragma unroll
        for (int qt = 0; qt < 4; ++qt) {
            o[qt][dt] = __builtin_amdgcn_mfma_f32_16x16x32_bf16(pa[qt][0], vf0, o[qt][dt], 0, 0, 0);
            o[qt][dt] = __builtin_amdgcn_mfma_f32_16x16x32_bf16(pa[qt][1], vf1, o[qt][dt], 0, 0, 0);
        }
    }
}

// R8: ZERO-GLOBAL MAIN LOOP. Evidence: R0 per-wave elapsed ~158K cy vs ~25K cy
// of accountable issue+latency, and R2 (true 16 waves/CU) did NOT raise
// per-SIMD busy (22%) -> waves queue on a SHARED resource, prime suspect the
// main loop's global K loads (L2/L3/fabric path). Register prefetch is closed:
// VGPR>128 halves residency (R4/R7: occ 16.6->9.8, dur 80; thrice-measured),
// and prefetch at cap 128 spills (R3).
// FIX: stage K bf16 into LDS in the prologue, MFMA-FRAGMENT-MAJOR (a wave's
// ds_read_b128 hits 64 consecutive 16B slots -> minimal 2-way/phase aliasing),
// alongside the V^T tiles. LDS = 64KB(V) + 64KB(K) = 128KB -> 1 block/CU,
// 4 waves/CU. Deliberate: R2 proved extra waves don't help (shared-resource
// stall), so losing residency is ~free while the main loop becomes pure
// LDS+MFMA+VALU (8 ds_read_b128/tile replace 8 global dwordx4 + 32 pkbf;
// K L2 traffic drops 2.5x: staged once vs 20 tile-uses).
// Block = 4 waves; wave w owns FULL query block n = n0 + w (4 independent qt
// softmax chains -- the proven-best per-wave ILP). Main loop barrier-free.
// V^T LDS layout: row d (0..63), 512 keys as 256 u32 bf16-pairs, column
// ROTATED by 8*d shorts (mod 512); 0 conflicts (measured R0).
__global__ __launch_bounds__(256, 1) void bsattn_kernel(
    const float* __restrict__ qg, const float* __restrict__ kg,
    const float* __restrict__ vg, float* __restrict__ outg)
{
    __shared__ unsigned int lds_vt[D_DIM * 256];   // 64 KB: V^T bf16 pairs, rotated
    __shared__ unsigned int lds_kf[8 * 2048];      // 64 KB: K bf16 fragment-major, 8 tiles

    const int tid  = threadIdx.x;
    const int w    = tid >> 6;
    const int lane = tid & 63;
    const int quad = lane >> 4;
    const int l16  = lane & 15;

    const int b  = blockIdx.z;
    const int h  = blockIdx.y;
    const int n0 = blockIdx.x << 2;
    const int n  = n0 + w;                       // this wave's query block

    // ---- Q fragments (B-operand): bq[qt][hh], pre-scaled, bf16 ----
    s16x8 bq[4][2];
#pragma unroll
    for (int qt = 0; qt < 4; ++qt) {
        const size_t qrow = ((size_t)(b * S_DIM + n * 64 + qt * 16 + l16) * H_DIM + h) * D_DIM;
#pragma unroll
        for (int hh = 0; hh < 2; ++hh) {
            const float4* qp = reinterpret_cast<const float4*>(qg + qrow + hh * 32 + quad * 8);
            float4 f0 = qp[0];
            float4 f1 = qp[1];
            u32x4 u;
            u.x = pkbf(f0.x * QSCALE, f0.y * QSCALE);
            u.y = pkbf(f0.z * QSCALE, f0.w * QSCALE);
            u.z = pkbf(f1.x * QSCALE, f1.y * QSCALE);
            u.w = pkbf(f1.z * QSCALE, f1.w * QSCALE);
            bq[qt][hh] = __builtin_bit_cast(s16x8, u);
        }
    }

    // ---- K staging: 8 tiles, fragment-major bf16 ----
    // Slot = (key 0..63, dchunk 0..7): 8 consecutive d at d0 = dchunk*8.
    // Reader lane l wants key = kt*16 + (l&15), d0 = (l>>4)*8 + hh*32
    //   -> lane = (key&15) + 16*(dchunk&3), frag idx = (key>>4)*2 + (dchunk>>2).
    // Global reads: 8 consecutive threads cover one 256B key row (coalesced).
#pragma unroll
    for (int jt = 0; jt < 8; ++jt) {
        const int jv = n0 - 2 + jt;
        if (jv < 0 || jv >= N_BLK) continue;
#pragma unroll
        for (int s = 0; s < 2; ++s) {
            const int slot = s * 256 + tid;
            const int key  = slot >> 3;
            const int dc   = slot & 7;
            const float* kp = kg + ((size_t)(b * S_DIM + jv * 64 + key) * H_DIM + h) * D_DIM + dc * 8;
            const float4 f0 = reinterpret_cast<const float4*>(kp)[0];
            const float4 f1 = reinterpret_cast<const float4*>(kp)[1];
            const u32x4 u = {pkbf(f0.x, f0.y), pkbf(f0.z, f0.w),
                             pkbf(f1.x, f1.y), pkbf(f1.z, f1.w)};
            const int lanew = (key & 15) + 16 * (dc & 3);
            const int fidx  = ((key >> 4) << 1) + (dc >> 2);
            *reinterpret_cast<u32x4*>(lds_kf + jt * 2048 + (fidx * 64 + lanew) * 4) = u;
        }
    }

    // ---- V^T staging: 8 tiles. thread -> (tile jt, row pair 2sp,2sp+1) ----
    {
        const int jt = tid >> 5;                 // 0..7
        const int sp = tid & 31;                 // row-pair index
        const int jv = n0 - 2 + jt;
        if (jv >= 0 && jv < N_BLK) {
            const float* v0p = vg + ((size_t)(b * S_DIM + jv * 64 + 2 * sp) * H_DIM + h) * D_DIM;
            const float* v1p = v0p + H_DIM * D_DIM;
            const int craw = jt * 64 + 2 * sp;   // raw column (key index) of this pair
#pragma unroll
            for (int ch = 0; ch < 4; ++ch) {     // 16 d-values per chunk (bounds transient regs)
                const int d0 = ch * 16;
                const float4* ap = reinterpret_cast<const float4*>(v0p + d0);
                const float4* bp = reinterpret_cast<const float4*>(v1p + d0);
                float4 a0 = ap[0], a1 = ap[1], a2 = ap[2], a3 = ap[3];
                float4 b0 = bp[0], b1 = bp[1], b2 = bp[2], b3 = bp[3];
                float av[16] = {a0.x,a0.y,a0.z,a0.w, a1.x,a1.y,a1.z,a1.w,
                                a2.x,a2.y,a2.z,a2.w, a3.x,a3.y,a3.z,a3.w};
                float bv[16] = {b0.x,b0.y,b0.z,b0.w, b1.x,b1.y,b1.z,b1.w,
                                b2.x,b2.y,b2.z,b2.w, b3.x,b3.y,b3.z,b3.w};
#pragma unroll
                for (int i = 0; i < 16; ++i) {
                    const int d = d0 + i;
                    lds_vt[d * 256 + (((craw + 8 * d) & 511) >> 1)] = pkbf(av[i], bv[i]);
                }
            }
        }
    }

    f32x4 o[4][4];                   // O accum [qt][dt], C layout (row=query, col=d)
    float m_run[4], l_run[4];
#pragma unroll
    for (int qt = 0; qt < 4; ++qt) {
        m_run[qt] = NEG_INF_F; l_run[qt] = 0.f;
#pragma unroll
        for (int dt = 0; dt < 4; ++dt) o[qt][dt] = (f32x4){0.f, 0.f, 0.f, 0.f};
    }

    __syncthreads();                 // K + V^T visible; no further barriers

    const int colb = quad * 4 + 8 * l16;     // V read-column base (rotation part w/o tile/dt)

    for (int t = 0; t < 5; ++t) {
        const int j = n - 2 + t;             // key block (wave-uniform)
        if (j < 0 || j >= N_BLK) continue;
        const int ji = w + t;                // staged tile index = j - n0 + 2

        // ---- K A-fragments from LDS (8 ds_read_b128, no global, no convert) ----
        const unsigned int* kfp = lds_kf + ji * 2048 + lane * 4;
        s16x8 kbf[4][2];
#pragma unroll
        for (int kt = 0; kt < 4; ++kt)
#pragma unroll
            for (int hh = 0; hh < 2; ++hh)
                kbf[kt][hh] = __builtin_bit_cast(s16x8,
                    *reinterpret_cast<const u32x4*>(kfp + ((kt << 1) + hh) * 256));

        compute_tile(kbf, bq, o, m_run, l_run, lds_vt, ji * 64 + colb, lane, quad);
    }

    // ---- epilogue: broadcast l to row layout, normalize, store ----
#pragma unroll
    for (int qt = 0; qt < 4; ++qt) {
#pragma unroll
        for (int r = 0; r < 4; ++r) {
            const float lb = __shfl(l_run[qt], (lane & 48) + quad * 4 + r);
            const float inv = 1.0f / lb;
            const int row = n * 64 + qt * 16 + quad * 4 + r;
            float* op = outg + ((size_t)(b * S_DIM + row) * H_DIM + h) * D_DIM + l16;
#pragma unroll
            for (int dt = 0; dt < 4; ++dt)
                op[dt * 16] = o[qt][dt][r] * inv;
        }
    }
}

extern "C" void kernel_launch(void* const* d_in, const int* in_sizes, int n_in,
                              void* d_out, int out_size, void* d_ws, size_t ws_size,
                              hipStream_t stream) {
    const float* q = (const float*)d_in[0];
    const float* k = (const float*)d_in[1];
    const float* v = (const float*)d_in[2];
    float* out = (float*)d_out;
    const int B = in_sizes[0] / (S_DIM * H_DIM * D_DIM);   // = 2
    dim3 grid(N_BLK / 4, H_DIM, B);
    dim3 block(256);
    hipLaunchKernelGGL(bsattn_kernel, grid, block, 0, stream, q, k, v, out);
}